// Round 1
// baseline (367.626 us; speedup 1.0000x reference)
//
#include <hip/hip_runtime.h>
#include <hip/hip_bf16.h>
#include <cstdint>

// KAN MLP: layers 256->512->512->256, B=8192, cubic B-splines on uniform grid
// (h=0.25, knots -1.75..1.75, 11 bases), BN fused into last GEMM epilogue.
//
// Strategy: per layer, expand activations to A[B, 12*fin] bf16
// ([gelu | 11 spline bases] per feature), pack weights to W[fout, 12*fin] bf16,
// then one bf16 MFMA GEMM h = A @ W^T with fp32 accumulate.
//
// Workspace layout (bytes), total 146,800,640 (~140 MB):
//   A    @ 0          : 8192*6144*2 = 100,663,296 (reused for all 3 layers)
//   W0   @ 100663296  : 512*3072*2  = 3,145,728
//   W1   @ 103809024  : 512*6144*2  = 6,291,456
//   W2   @ 110100480  : 256*6144*2  = 3,145,728
//   H1   @ 113246208  : 8192*512*4  = 16,777,216
//   H2   @ 130023424  : 8192*512*4  = 16,777,216

typedef unsigned short ushort_t;
typedef __bf16 bf16x8 __attribute__((ext_vector_type(8)));
typedef float f32x4 __attribute__((ext_vector_type(4)));

__device__ __forceinline__ ushort_t f2bf(float f) {
    __bf16 h = (__bf16)f;  // RNE
    return __builtin_bit_cast(ushort_t, h);
}

// async global->LDS 16B copy. LDS dest must be wave-uniform base + lane*16.
__device__ __forceinline__ void gload_lds16(const void* g, void* lds) {
    __builtin_amdgcn_global_load_lds(
        (const __attribute__((address_space(1))) unsigned int*)(uintptr_t)g,
        (__attribute__((address_space(3))) unsigned int*)(unsigned int)(uintptr_t)lds,
        16, 0, 0);
}

// ---------------------------------------------------------------------------
// Weight pack: W[o][i*12+0] = base_w[o][i]; W[o][i*12+1+k] = spline_w[o][i][k]
// idx = o*fin + i (layouts of base_w (fout,fin) and spline_w (fout,fin,11)
// both linearize to this).
// ---------------------------------------------------------------------------
__global__ __launch_bounds__(256) void pack_w_kernel(
    const float* __restrict__ bw, const float* __restrict__ sw,
    ushort_t* __restrict__ W, int total)
{
    int idx = blockIdx.x * 256 + threadIdx.x;
    if (idx >= total) return;
    union { ushort_t us[12]; uint2 v[3]; } pk;
    pk.us[0] = f2bf(bw[idx]);
    const float* s = sw + (size_t)idx * 11;
#pragma unroll
    for (int k = 0; k < 11; ++k) pk.us[1 + k] = f2bf(s[k]);
    uint2* dst = (uint2*)(W + (size_t)idx * 12);  // byte offset idx*24, 8B aligned
    dst[0] = pk.v[0]; dst[1] = pk.v[1]; dst[2] = pk.v[2];
}

// ---------------------------------------------------------------------------
// Expansion: X[B,fin] fp32 -> A[B, fin*12] bf16 = [gelu, bases 0..10] per feat.
// Uniform-grid cubic B-spline closed form (matches reference recursion).
// ---------------------------------------------------------------------------
__global__ __launch_bounds__(256) void expand_kernel(
    const float* __restrict__ X, ushort_t* __restrict__ A, int total)
{
    int idx = blockIdx.x * 256 + threadIdx.x;
    if (idx >= total) return;
    float x = X[idx];
    float gelu = 0.5f * x * (1.0f + erff(x * 0.70710678118654752440f));

    float xs = (x + 1.75f) * 4.0f;      // knot-interval coordinate
    float fs = floorf(xs);
    int   s  = (int)fs;
    float u  = xs - fs;
    bool  inr = (s >= 0) && (s <= 13);
    float u2 = u * u, u3 = u2 * u;
    float om = 1.0f - u;
    const float c6 = 1.0f / 6.0f;
    float w0 = om * om * om * c6;                          // basis s-3
    float w1 = (3.0f * u3 - 6.0f * u2 + 4.0f) * c6;        // basis s-2
    float w2 = (-3.0f * u3 + 3.0f * u2 + 3.0f * u + 1.0f) * c6; // basis s-1
    float w3 = u3 * c6;                                    // basis s

    union { ushort_t us[12]; uint2 v[3]; } pk;
    pk.us[0] = f2bf(gelu);
#pragma unroll
    for (int j = 0; j < 11; ++j) {
        float v = 0.0f;
        if (inr) {
            if (j == s - 3)      v = w0;
            else if (j == s - 2) v = w1;
            else if (j == s - 1) v = w2;
            else if (j == s)     v = w3;
        }
        pk.us[1 + j] = f2bf(v);
    }
    uint2* dst = (uint2*)(A + (size_t)idx * 12);
    dst[0] = pk.v[0]; dst[1] = pk.v[1]; dst[2] = pk.v[2];
}

// ---------------------------------------------------------------------------
// GEMM: C[M,N] fp32 = A[M,K]bf16 @ W[N,K]bf16^T, optional fused BN on columns.
// Tile 128(M) x 64(N), BK=64, 256 threads = 4 waves in 2x2 (each wave 64x32).
// mfma_f32_16x16x32_bf16; XOR swizzle on 16B chunks breaks ds_read_b128 bank
// conflicts (swizzle applied to the GLOBAL source chunk since global_load_lds
// LDS dest is fixed at base+lane*16).
//   A frag: lane holds A[m=lane&15][k=(lane>>4)*8 + j]  (j=0..7)
//   B frag: lane holds W[n=lane&15][k=(lane>>4)*8 + j]
//   C/D   : lane holds D[m=(lane>>4)*4+r][n=lane&15]
// ---------------------------------------------------------------------------
template <bool FUSE_BN>
__global__ __launch_bounds__(256) void gemm_kernel(
    const ushort_t* __restrict__ A,  // M x K
    const ushort_t* __restrict__ W,  // N x K
    float* __restrict__ C,           // M x N
    int M, int N, int K,
    const float* __restrict__ gamma, const float* __restrict__ beta,
    const float* __restrict__ mean,  const float* __restrict__ var)
{
    __shared__ __align__(16) ushort_t As[128 * 64];  // 16 KB
    __shared__ __align__(16) ushort_t Bs[64 * 64];   // 8 KB

    const int t  = threadIdx.x;
    const int l  = t & 63;
    const int w  = t >> 6;
    const int wm = w >> 1;       // 0..1 -> +64*wm rows
    const int wn = w & 1;        // 0..1 -> +32*wn cols
    const int blockM = blockIdx.x * 128;
    const int blockN = blockIdx.y * 64;
    const int l15 = l & 15;
    const int q   = l >> 4;

    f32x4 acc[4][2];
#pragma unroll
    for (int i = 0; i < 4; ++i)
#pragma unroll
        for (int j = 0; j < 2; ++j) acc[i][j] = (f32x4){0.f, 0.f, 0.f, 0.f};

    const int kb_steps = K >> 6;
    for (int kb = 0; kb < kb_steps; ++kb) {
        const int k0 = kb << 6;
        // --- stage A tile: 128 rows x 64 cols = 1024 16B-chunks, 4/thread ---
#pragma unroll
        for (int it = 0; it < 4; ++it) {
            int s   = it * 256 + t;           // LDS slot; within a wave,
            int row = s >> 3, c = s & 7;      // slots are lane-consecutive
            int g   = c ^ (row & 7);          // swizzled global chunk
            gload_lds16(A + ((size_t)(blockM + row) * K + k0 + g * 8), &As[s * 8]);
        }
        // --- stage B tile: 64 rows x 64 cols = 512 chunks, 2/thread ---
#pragma unroll
        for (int it = 0; it < 2; ++it) {
            int s   = it * 256 + t;
            int row = s >> 3, c = s & 7;
            int g   = c ^ (row & 7);
            gload_lds16(W + ((size_t)(blockN + row) * K + k0 + g * 8), &Bs[s * 8]);
        }
        __syncthreads();  // compiler emits vmcnt(0) drain before s_barrier

        // --- compute: 2 k-steps of 32, 4x2 mfma tiles per wave ---
#pragma unroll
        for (int ks = 0; ks < 2; ++ks) {
            bf16x8 af[4], bf[2];
#pragma unroll
            for (int mi = 0; mi < 4; ++mi) {
                int m  = wm * 64 + mi * 16 + l15;
                int cs = (ks * 4 + q) ^ (m & 7);
                af[mi] = *(const bf16x8*)&As[m * 64 + cs * 8];
            }
#pragma unroll
            for (int ni = 0; ni < 2; ++ni) {
                int n  = wn * 32 + ni * 16 + l15;
                int cs = (ks * 4 + q) ^ (n & 7);
                bf[ni] = *(const bf16x8*)&Bs[n * 64 + cs * 8];
            }
#pragma unroll
            for (int mi = 0; mi < 4; ++mi)
#pragma unroll
                for (int ni = 0; ni < 2; ++ni)
                    acc[mi][ni] = __builtin_amdgcn_mfma_f32_16x16x32_bf16(
                        af[mi], bf[ni], acc[mi][ni], 0, 0, 0);
        }
        __syncthreads();
    }

    // --- epilogue ---
#pragma unroll
    for (int ni = 0; ni < 2; ++ni) {
        int n = blockN + wn * 32 + ni * 16 + l15;
        float scale = 1.0f, bias = 0.0f;
        if (FUSE_BN) {
            float sc = gamma[n] * rsqrtf(var[n] + 1e-5f);
            scale = sc;
            bias  = beta[n] - mean[n] * sc;
        }
#pragma unroll
        for (int mi = 0; mi < 4; ++mi) {
            int mbase = blockM + wm * 64 + mi * 16 + q * 4;
#pragma unroll
            for (int r = 0; r < 4; ++r) {
                float v = acc[mi][ni][r];
                if (FUSE_BN) v = v * scale + bias;
                C[(size_t)(mbase + r) * N + n] = v;
            }
        }
    }
}

// ---------------------------------------------------------------------------
extern "C" void kernel_launch(void* const* d_in, const int* in_sizes, int n_in,
                              void* d_out, int out_size, void* d_ws, size_t ws_size,
                              hipStream_t stream) {
    const float* x     = (const float*)d_in[0];
    const float* bw0   = (const float*)d_in[2];
    const float* sw0   = (const float*)d_in[3];
    const float* bw1   = (const float*)d_in[5];
    const float* sw1   = (const float*)d_in[6];
    const float* bw2   = (const float*)d_in[8];
    const float* sw2   = (const float*)d_in[9];
    const float* gamma = (const float*)d_in[10];
    const float* beta  = (const float*)d_in[11];
    const float* mean  = (const float*)d_in[12];
    const float* var   = (const float*)d_in[13];

    char* ws = (char*)d_ws;
    ushort_t* Abuf = (ushort_t*)(ws);
    ushort_t* W0   = (ushort_t*)(ws + 100663296);
    ushort_t* W1   = (ushort_t*)(ws + 103809024);
    ushort_t* W2   = (ushort_t*)(ws + 110100480);
    float*    H1   = (float*)(ws + 113246208);
    float*    H2   = (float*)(ws + 130023424);
    float*    out  = (float*)d_out;

    // weight packing (d_ws is re-poisoned every call, so repack every call)
    pack_w_kernel<<<(512 * 256 + 255) / 256, 256, 0, stream>>>(bw0, sw0, W0, 512 * 256);
    pack_w_kernel<<<(512 * 512 + 255) / 256, 256, 0, stream>>>(bw1, sw1, W1, 512 * 512);
    pack_w_kernel<<<(256 * 512 + 255) / 256, 256, 0, stream>>>(bw2, sw2, W2, 256 * 512);

    // layer 0: fin=256 (K=3072), fout=512
    expand_kernel<<<(8192 * 256) / 256, 256, 0, stream>>>(x, Abuf, 8192 * 256);
    {
        dim3 g(8192 / 128, 512 / 64);
        gemm_kernel<false><<<g, 256, 0, stream>>>(Abuf, W0, H1, 8192, 512, 3072,
                                                  nullptr, nullptr, nullptr, nullptr);
    }
    // layer 1: fin=512 (K=6144), fout=512
    expand_kernel<<<(8192 * 512) / 256, 256, 0, stream>>>(H1, Abuf, 8192 * 512);
    {
        dim3 g(8192 / 128, 512 / 64);
        gemm_kernel<false><<<g, 256, 0, stream>>>(Abuf, W1, H2, 8192, 512, 6144,
                                                  nullptr, nullptr, nullptr, nullptr);
    }
    // layer 2: fin=512 (K=6144), fout=256, BN fused
    expand_kernel<<<(8192 * 512) / 256, 256, 0, stream>>>(H2, Abuf, 8192 * 512);
    {
        dim3 g(8192 / 128, 256 / 64);
        gemm_kernel<true><<<g, 256, 0, stream>>>(Abuf, W2, out, 8192, 256, 6144,
                                                 gamma, beta, mean, var);
    }
}